// Round 5
// baseline (5007.290 us; speedup 1.0000x reference)
//
#include <hip/hip_runtime.h>
#include <stdint.h>

#define D_H    300
#define D_HP   304      // padded message row stride (elements)
#define NBND   400001   // bonds + 1 zero-pad row
#define NATM   200000
#define MAXNB  6
#define AFD    133
#define IFD    147
#define K1_I   160      // padded f_ini K segment (mult of 16)
#define K1_A   144      // padded atom_features K segment (mult of 16)
#define LDB_IH (K1_I + D_HP)   // 464 = [W_i | W_h] concat row stride
#define LDB_OM (K1_A + D_HP)   // 448 = [W_oa | W_om] concat row stride
#define NMOLS  1000
#define APM    200
#define GFD    2048
#define OUTW   (D_H + GFD)     // 2348
#define WROWS  320
#define BM 64
#define BN 320

typedef unsigned short bf16_t;

__device__ __forceinline__ float frelu(float x) { return x > 0.f ? x : 0.f; }

__device__ __forceinline__ float b2f(bf16_t u) {
    union { unsigned int i; float f; } v; v.i = ((unsigned int)u) << 16; return v.f;
}
__device__ __forceinline__ bf16_t f2b(float f) {   // round-to-nearest-even
    union { float f; unsigned int i; } v; v.f = f;
    unsigned int x = v.i;
    x += 0x7fffu + ((x >> 16) & 1u);
    return (bf16_t)(x >> 16);
}

// ---- diagnostic: encode ws budget in the output when ws is insufficient ----
__global__ __launch_bounds__(256) void fill_sentinel(float* __restrict__ out, int n, float val)
{
    int t = blockIdx.x * 256 + threadIdx.x;
    int stride = gridDim.x * 256;
    for (int i = t; i < n; i += stride) out[i] = val;
}

// ---- weight prep: WcatIH [320][464] = [Wi(147)|pad|Wh(300)|pad], zero-padded
//      WcatOM [320][448] = [Woa(133)|pad|Wom(300)|pad]
__global__ __launch_bounds__(256) void prep_weights(
    const float* __restrict__ Wi, const float* __restrict__ Wh,
    const float* __restrict__ Wow,
    float* __restrict__ WcatIH, float* __restrict__ WcatOM)
{
    int t = blockIdx.x * 256 + threadIdx.x;
    int stride = gridDim.x * 256;
    for (int i = t; i < WROWS * LDB_IH; i += stride) {
        int r = i / LDB_IH, c = i - r * LDB_IH;
        float v = 0.f;
        if (r < D_H) {
            if (c < IFD)                          v = Wi[r * IFD + c];
            else if (c >= K1_I && c < K1_I + D_H) v = Wh[r * D_H + (c - K1_I)];
        }
        WcatIH[i] = v;
    }
    for (int i = t; i < WROWS * LDB_OM; i += stride) {
        int r = i / LDB_OM, c = i - r * LDB_OM;
        float v = 0.f;
        if (r < D_H) {
            if (c < AFD)                          v = Wow[r * (AFD + D_H) + c];
            else if (c >= K1_A && c < K1_A + D_H) v = Wow[r * (AFD + D_H) + AFD + (c - K1_A)];
        }
        WcatOM[i] = v;
    }
}

// ---- two-segment fused GEMM: out[r] = relu( A1_row @ B1^T + gathersum @ B2^T (+bias) )
// B = [B1 | B2] concatenated along K (fp32, row stride ldb). Gather source G and
// output are bf16 (payload compression); all math fp32 in-register.
// Tile BM=64 x BN=320 (all 300 cols in one block-col so each row's 6-way gather
// happens exactly once per 16-chunk of K2). 256 threads: 4 rows x 20 cols each.
template<bool HAS_GATHER, bool HAS_BIAS>
__global__ __launch_bounds__(256) void gemm_two_seg(
    const float*  __restrict__ A1,    // packed features [M][lda1] fp32
    const bf16_t* __restrict__ G,     // gather source [NBND][D_HP] bf16
    const float*  __restrict__ B,     // [320][ldb] padded weights fp32
    const int*    __restrict__ idx,   // [M][6] gather indices (if HAS_GATHER)
    const float*  __restrict__ bias,  // [300] (if HAS_BIAS)
    bf16_t* __restrict__ out,         // [M][D_HP] bf16, relu'd, pad cols zeroed
    int M, int K1, int K2, int lda1, size_t a1max, int ldb)
{
    __shared__ float As[16][BM];
    __shared__ float Bs[16][BN];
    __shared__ int   map6[BM * MAXNB];

    const int tid  = threadIdx.x;
    const int row0 = blockIdx.x * BM;
    const int tx4  = (tid & 15) * 4;   // output col base (within 64-col group)
    const int ty4  = (tid >> 4) * 4;   // output row base
    const int la   = tid >> 2;         // 0..63: staging row
    const int lk   = (tid & 3) * 4;    // 0,4,8,12: staging k-quad

    int mj[MAXNB];
    if (HAS_GATHER) {
        for (int i = tid; i < BM * MAXNB; i += 256) {
            long g  = (long)row0 * MAXNB + i;
            long gm = (long)M * MAXNB - 1;
            map6[i] = idx[g > gm ? gm : g];
        }
        __syncthreads();
        #pragma unroll
        for (int j = 0; j < MAXNB; ++j) mj[j] = map6[la * MAXNB + j];
    }

    float4 acc[4][5];
    #pragma unroll
    for (int i = 0; i < 4; ++i)
        #pragma unroll
        for (int w = 0; w < 5; ++w) acc[i][w] = make_float4(0.f, 0.f, 0.f, 0.f);

    const int arow = (row0 + la < M) ? (row0 + la) : (M - 1);
    const int K = K1 + K2;

    for (int k0 = 0; k0 < K; k0 += 16) {
        // ---- stage A quad into regs ----
        float4 av;
        if (!HAS_GATHER || k0 < K1) {
            // packed fp32 segment; cols >= lda1 read stray data x zero weights
            size_t b0 = (size_t)arow * lda1 + (size_t)(k0 + lk);
            size_t i0 = b0, i1 = b0 + 1, i2 = b0 + 2, i3 = b0 + 3;
            av.x = A1[i0 > a1max ? a1max : i0];
            av.y = A1[i1 > a1max ? a1max : i1];
            av.z = A1[i2 > a1max ? a1max : i2];
            av.w = A1[i3 > a1max ? a1max : i3];
        } else {
            const int kg = k0 - K1 + lk;
            av = make_float4(0.f, 0.f, 0.f, 0.f);
            #pragma unroll
            for (int j = 0; j < MAXNB; ++j) {
                const ushort4 v = *(const ushort4*)&G[(size_t)mj[j] * D_HP + kg];
                av.x += b2f(v.x); av.y += b2f(v.y);
                av.z += b2f(v.z); av.w += b2f(v.w);
            }
        }
        // ---- stage B quads (5 groups of 64 weight rows) ----
        float4 bv[5];
        #pragma unroll
        for (int w = 0; w < 5; ++w)
            bv[w] = *(const float4*)&B[(size_t)(64 * w + la) * ldb + (size_t)(k0 + lk)];

        __syncthreads();   // previous iteration's LDS reads done
        As[lk + 0][la] = av.x; As[lk + 1][la] = av.y;
        As[lk + 2][la] = av.z; As[lk + 3][la] = av.w;
        #pragma unroll
        for (int w = 0; w < 5; ++w) {
            const int h = 64 * w + la;
            Bs[lk + 0][h] = bv[w].x; Bs[lk + 1][h] = bv[w].y;
            Bs[lk + 2][h] = bv[w].z; Bs[lk + 3][h] = bv[w].w;
        }
        __syncthreads();

        #pragma unroll
        for (int kk = 0; kk < 16; ++kk) {
            const float4 a4 = *(const float4*)&As[kk][ty4];
            float4 b[5];
            #pragma unroll
            for (int w = 0; w < 5; ++w) b[w] = *(const float4*)&Bs[kk][tx4 + 64 * w];
            const float a_[4] = {a4.x, a4.y, a4.z, a4.w};
            #pragma unroll
            for (int i = 0; i < 4; ++i)
                #pragma unroll
                for (int w = 0; w < 5; ++w) {
                    acc[i][w].x += a_[i] * b[w].x;
                    acc[i][w].y += a_[i] * b[w].y;
                    acc[i][w].z += a_[i] * b[w].z;
                    acc[i][w].w += a_[i] * b[w].w;
                }
        }
    }

    // ---- epilogue: relu (+bias) -> bf16; zero pad quad 300..303 ----
    #pragma unroll
    for (int i = 0; i < 4; ++i) {
        const int r = row0 + ty4 + i;
        if (r >= M) continue;
        #pragma unroll
        for (int w = 0; w < 5; ++w) {
            const float vals[4] = {acc[i][w].x, acc[i][w].y, acc[i][w].z, acc[i][w].w};
            const int c = tx4 + 64 * w;          // quad base, multiple of 4
            if (c >= D_HP) continue;             // cols 304..319 don't exist
            ushort4 q;
            if (c < D_H) {                        // quad entirely < 300 (300 % 4 == 0)
                float v0 = vals[0], v1 = vals[1], v2 = vals[2], v3 = vals[3];
                if (HAS_BIAS) { v0 += bias[c]; v1 += bias[c+1]; v2 += bias[c+2]; v3 += bias[c+3]; }
                q.x = f2b(frelu(v0)); q.y = f2b(frelu(v1));
                q.z = f2b(frelu(v2)); q.w = f2b(frelu(v3));
            } else {                              // pad quad 300..303: zero (read by gathers)
                q.x = q.y = q.z = q.w = 0;
            }
            *(ushort4*)&out[(size_t)r * D_HP + c] = q;
        }
    }
}

// ---- readout: per-mol mean over 200 atoms (bf16 in, fp32 acc) + concat gf ----
__global__ __launch_bounds__(320) void readout(
    const bf16_t* __restrict__ atoms_h, const float* __restrict__ gf,
    float* __restrict__ out)
{
    const int m = blockIdx.x;
    const int t = threadIdx.x;
    if (t < D_H) {
        float s = 0.f;
        const bf16_t* p = atoms_h + (size_t)m * APM * D_HP + t;
        #pragma unroll 4
        for (int a = 0; a < APM; ++a) s += b2f(p[(size_t)a * D_HP]);
        out[(size_t)m * OUTW + t] = s * (1.f / APM);
    }
    for (int c = t; c < GFD; c += 320) {
        out[(size_t)m * OUTW + D_H + c] = gf[(size_t)m * GFD + c];
    }
}

extern "C" void kernel_launch(void* const* d_in, const int* in_sizes, int n_in,
                              void* d_out, int out_size, void* d_ws, size_t ws_size,
                              hipStream_t stream)
{
    const float* atom_features = (const float*)d_in[0];
    const float* f_ini         = (const float*)d_in[1];
    const int*   a2b           = (const int*)d_in[2];
    const int*   mapping       = (const int*)d_in[3];
    const float* gfeat         = (const float*)d_in[4];
    const float* Wi            = (const float*)d_in[5];
    const float* Wh            = (const float*)d_in[6];
    const float* Wow           = (const float*)d_in[7];
    const float* Wob           = (const float*)d_in[8];

    char* ws = (char*)d_ws;
    size_t off = 0;
    auto alloc = [&](size_t bytes) {
        void* p = ws + off;
        off += (bytes + 255) & ~(size_t)255;
        return p;
    };
    float*  WcatIH = (float*)alloc((size_t)WROWS * LDB_IH * 4);   // 0.57 MB
    float*  WcatOM = (float*)alloc((size_t)WROWS * LDB_OM * 4);   // 0.55 MB
    bf16_t* msgA   = (bf16_t*)alloc((size_t)NBND * D_HP * 2);     // 243.2 MB
    bf16_t* msgB   = (bf16_t*)alloc((size_t)NBND * D_HP * 2);     // 243.2 MB
    bf16_t* atoms  = msgB;  // msgB dead after MP round 2; atoms needs 121.6 MB

    if (off > ws_size) {
        // ws too small (~488 MiB needed). Encode the actual budget in the
        // sentinel: absmax will read ~= 1e6 + ws_MiB.
        float v = 1.0e6f + (float)(ws_size >> 20);
        fill_sentinel<<<1024, 256, 0, stream>>>((float*)d_out, out_size, v);
        return;
    }

    prep_weights<<<600, 256, 0, stream>>>(Wi, Wh, Wow, WcatIH, WcatOM);

    const int gb = (NBND + BM - 1) / BM;   // 6251
    const int ga = (NATM + BM - 1) / BM;   // 3125
    const size_t fmax = (size_t)NBND * IFD - 1;
    const size_t amax = (size_t)NATM * AFD - 1;

    // msgA = relu(f_ini @ Wi^T)
    gemm_two_seg<false, false><<<gb, 256, 0, stream>>>(
        f_ini, nullptr, WcatIH, nullptr, nullptr, msgA,
        NBND, K1_I, 0, IFD, fmax, LDB_IH);
    // msgB = relu(f_ini @ Wi^T + gather6(msgA) @ Wh^T)
    gemm_two_seg<true, false><<<gb, 256, 0, stream>>>(
        f_ini, msgA, WcatIH, mapping, nullptr, msgB,
        NBND, K1_I, D_HP, IFD, fmax, LDB_IH);
    // msgA = relu(f_ini @ Wi^T + gather6(msgB) @ Wh^T)
    gemm_two_seg<true, false><<<gb, 256, 0, stream>>>(
        f_ini, msgB, WcatIH, mapping, nullptr, msgA,
        NBND, K1_I, D_HP, IFD, fmax, LDB_IH);
    // atoms = relu(atom_features @ Woa^T + gather6(msgA) @ Wom^T + b)
    gemm_two_seg<true, true><<<ga, 256, 0, stream>>>(
        atom_features, msgA, WcatOM, a2b, Wob, atoms,
        NATM, K1_A, D_HP, AFD, amax, LDB_OM);

    readout<<<NMOLS, 320, 0, stream>>>(atoms, gfeat, (float*)d_out);
}

// Round 7
// 2666.214 us; speedup vs baseline: 1.8781x; 1.8781x over previous
//
#include <hip/hip_runtime.h>
#include <stdint.h>

#define D_H    300
#define D_HP   304      // message row stride (elements); 608 B, 16B-aligned
#define NBND   400001
#define NATM   200000
#define MAXNB  6
#define AFD    133
#define IFD    147
#define KSEG1  160      // first K segment (features), mult of 32, covers 147/133
#define K2P    320      // padded gather K segment (mult of 32, covers 304)
#define LDW    480      // bf16 weight concat row stride = KSEG1 + K2P
#define KT_S1  160
#define KT_MP  480
#define NMOLS  1000
#define APM    200
#define GFD    2048
#define OUTW   2348
#define WROWS  320
#define BM     64

typedef unsigned short bf16_t;
typedef __attribute__((ext_vector_type(8))) short  s8v;   // 8 bf16 = 4 VGPRs
typedef __attribute__((ext_vector_type(4))) float  f4v;   // MFMA accumulator

__device__ __forceinline__ float frelu(float x) { return x > 0.f ? x : 0.f; }
__device__ __forceinline__ float b2f_lo(unsigned u) {
    union { unsigned i; float f; } v; v.i = u << 16; return v.f;
}
__device__ __forceinline__ float b2f_hi(unsigned u) {
    union { unsigned i; float f; } v; v.i = u & 0xffff0000u; return v.f;
}
__device__ __forceinline__ bf16_t f2b(float f) {   // RTNE
    union { float f; unsigned i; } v; v.f = f;
    unsigned x = v.i + 0x7fffu + ((v.i >> 16) & 1u);
    return (bf16_t)(x >> 16);
}

// ---- diagnostic: encode ws budget in output if ws insufficient ----
__global__ __launch_bounds__(256) void fill_sentinel(float* __restrict__ out, int n, float val)
{
    int t = blockIdx.x * 256 + threadIdx.x;
    int stride = gridDim.x * 256;
    for (int i = t; i < n; i += stride) out[i] = val;
}

// ---- weight prep (fp32 -> bf16 concat, zero-padded) ----
// WIH [320][480] = [Wi(147)|0|Wh(300)|0] ; WOM [320][480] = [Woa(133)|0|Wom(300)|0]
__global__ __launch_bounds__(256) void prep_weights(
    const float* __restrict__ Wi, const float* __restrict__ Wh,
    const float* __restrict__ Wow,
    bf16_t* __restrict__ WIH, bf16_t* __restrict__ WOM)
{
    int t = blockIdx.x * 256 + threadIdx.x;
    int stride = gridDim.x * 256;
    for (int i = t; i < WROWS * LDW; i += stride) {
        int r = i / LDW, c = i - r * LDW;
        float vih = 0.f, vom = 0.f;
        if (r < D_H) {
            if (c < IFD)                           vih = Wi[r * IFD + c];
            else if (c >= KSEG1 && c < KSEG1+D_H)  vih = Wh[r * D_H + (c - KSEG1)];
            if (c < AFD)                           vom = Wow[r * (AFD + D_H) + c];
            else if (c >= KSEG1 && c < KSEG1+D_H)  vom = Wow[r * (AFD + D_H) + AFD + (c - KSEG1)];
        }
        WIH[i] = f2b(vih);
        WOM[i] = f2b(vom);
    }
}

// ---- MFMA two-segment fused GEMM ----
// out[r][h] = relu( A1row(bf16-cast) @ W[:, :160]^T + gathersum6(G) @ W[:, 160:]^T (+bias) )
// BM=64 rows x 320 cols per block, 4 waves; each wave: all 4 row-tiles x 5 col-tiles.
// LDS chunk layout [kg][row] of bf16x8 -> frag read = 1x ds_read_b128, conflict-free.
// B staged via global_load_lds (linear dest = base+lane*16, per-lane source).
template<bool HAS_GATHER, bool HAS_BIAS>
__global__ __launch_bounds__(256, 2) void gemm_mfma(
    const float*  __restrict__ A1,    // packed features [M][lda1] fp32
    const bf16_t* __restrict__ G,     // gather source [NBND][D_HP] bf16
    const bf16_t* __restrict__ W,     // [320][LDW] bf16 concat weights
    const int*    __restrict__ idx,   // [M][6]
    const float*  __restrict__ bias,  // [300]
    bf16_t* __restrict__ out,         // [M][D_HP] bf16
    int M, int KT, int lda1, size_t a1max)
{
    __shared__ s8v AsV[4 * 64];    // [kg][row]  4 KB
    __shared__ s8v BsV[4 * 320];   // [kg][col] 20 KB

    const int tid  = threadIdx.x;
    const int lane = tid & 63;
    const int wv   = tid >> 6;
    const int row0 = blockIdx.x * BM;

    // staging task: one (row, k-octet) per thread
    const int sr = tid >> 2;                 // 0..63 block-local row
    const int kg = tid & 3;                  // k-octet within 32-k step
    int gr = row0 + sr; if (gr > M - 1) gr = M - 1;

    int mj[MAXNB];
    if (HAS_GATHER) {
        #pragma unroll
        for (int j = 0; j < MAXNB; ++j) mj[j] = idx[(size_t)gr * MAXNB + j];
    }

    f4v acc[4][5];
    #pragma unroll
    for (int rt = 0; rt < 4; ++rt)
        #pragma unroll
        for (int j = 0; j < 5; ++j) { f4v z = {0.f, 0.f, 0.f, 0.f}; acc[rt][j] = z; }

    const int fr = lane & 15;      // frag row/col within 16-tile
    const int fg = lane >> 4;      // frag k-group

    for (int kt = 0; kt < KT; kt += 32) {
        // ---- stage B: 1280 16B chunks via global_load_lds (5 per thread-slot) ----
        #pragma unroll
        for (int is = 0; is < 5; ++is) {
            const int c    = is * 256 + tid;        // 0..1279, lane-contiguous per wave
            const int bkg  = c / 320;
            const int bcol = c - bkg * 320;
            const bf16_t* src = &W[(size_t)bcol * LDW + (kt + bkg * 8)];
            __builtin_amdgcn_global_load_lds(
                (const __attribute__((address_space(1))) void*)src,
                (__attribute__((address_space(3))) void*)&BsV[c], 16, 0, 0);
        }

        // ---- stage A: one bf16x8 chunk per thread ----
        const int k0 = kt + kg * 8;
        bf16_t h0, h1, h2, h3, h4, h5, h6, h7;
        if (!HAS_GATHER || kt < KSEG1) {
            // feature segment: fp32 -> bf16, per-element clamped (pad cols x zero weights)
            float f[8];
            #pragma unroll
            for (int j = 0; j < 8; ++j) {
                size_t a = (size_t)gr * lda1 + (size_t)(k0 + j);
                if (a > a1max) a = a1max;
                f[j] = A1[a];
            }
            h0 = f2b(f[0]); h1 = f2b(f[1]); h2 = f2b(f[2]); h3 = f2b(f[3]);
            h4 = f2b(f[4]); h5 = f2b(f[5]); h6 = f2b(f[6]); h7 = f2b(f[7]);
        } else {
            const int kk = k0 - KSEG1;          // 0..312, chunks never straddle 304
            float s0=0,s1=0,s2=0,s3=0,s4=0,s5=0,s6=0,s7=0;
            if (kk < D_HP) {
                #pragma unroll
                for (int j = 0; j < MAXNB; ++j) {
                    const uint4 g = *(const uint4*)&G[(size_t)mj[j] * D_HP + kk];
                    s0 += b2f_lo(g.x); s1 += b2f_hi(g.x);
                    s2 += b2f_lo(g.y); s3 += b2f_hi(g.y);
                    s4 += b2f_lo(g.z); s5 += b2f_hi(g.z);
                    s6 += b2f_lo(g.w); s7 += b2f_hi(g.w);
                }
            }
            h0 = f2b(s0); h1 = f2b(s1); h2 = f2b(s2); h3 = f2b(s3);
            h4 = f2b(s4); h5 = f2b(s5); h6 = f2b(s6); h7 = f2b(s7);
        }
        {
            s8v av;
            av[0] = (short)h0; av[1] = (short)h1; av[2] = (short)h2; av[3] = (short)h3;
            av[4] = (short)h4; av[5] = (short)h5; av[6] = (short)h6; av[7] = (short)h7;
            AsV[kg * 64 + sr] = av;
        }

        __syncthreads();   // drains vmcnt (gload_lds) + lgkm (ds_write)

        // ---- compute: 4 row-tiles x 5 col-tiles, K=32 ----
        s8v a[4];
        #pragma unroll
        for (int rt = 0; rt < 4; ++rt) a[rt] = AsV[fg * 64 + rt * 16 + fr];
        #pragma unroll
        for (int j = 0; j < 5; ++j) {
            const int nt = wv * 5 + j;
            const s8v b = BsV[fg * 320 + nt * 16 + fr];
            #pragma unroll
            for (int rt = 0; rt < 4; ++rt)
                acc[rt][j] = __builtin_amdgcn_mfma_f32_16x16x32_bf16(a[rt], b, acc[rt][j], 0, 0, 0);
        }

        __syncthreads();   // protect LDS before next stage
    }

    // ---- epilogue: relu(+bias) -> bf16. C/D: col=lane&15, row=(lane>>4)*4+reg ----
    #pragma unroll
    for (int j = 0; j < 5; ++j) {
        const int nt = wv * 5 + j;
        if (nt >= 19) continue;            // cols 304..319: pure pad, not stored
        const int c = nt * 16 + fr;        // 0..303; cols 300..303 compute 0 (zero W rows)
        float bc = 0.f;
        if (HAS_BIAS) bc = (c < D_H) ? bias[c] : 0.f;
        #pragma unroll
        for (int rt = 0; rt < 4; ++rt) {
            #pragma unroll
            for (int q = 0; q < 4; ++q) {
                const int r = row0 + rt * 16 + fg * 4 + q;
                if (r < M) out[(size_t)r * D_HP + c] = f2b(frelu(acc[rt][j][q] + bc));
            }
        }
    }
}

// ---- readout: per-mol mean over 200 atoms (bf16 in, fp32 acc) + concat gf ----
__global__ __launch_bounds__(320) void readout(
    const bf16_t* __restrict__ atoms_h, const float* __restrict__ gf,
    float* __restrict__ out)
{
    const int m = blockIdx.x;
    const int t = threadIdx.x;
    if (t < D_H) {
        float s = 0.f;
        const bf16_t* p = atoms_h + (size_t)m * APM * D_HP + t;
        #pragma unroll 4
        for (int a = 0; a < APM; ++a) s += b2f_lo((unsigned)p[(size_t)a * D_HP]);
        out[(size_t)m * OUTW + t] = s * (1.f / APM);
    }
    for (int c = t; c < GFD; c += 320) {
        out[(size_t)m * OUTW + D_H + c] = gf[(size_t)m * GFD + c];
    }
}

extern "C" void kernel_launch(void* const* d_in, const int* in_sizes, int n_in,
                              void* d_out, int out_size, void* d_ws, size_t ws_size,
                              hipStream_t stream)
{
    const float* atom_features = (const float*)d_in[0];
    const float* f_ini         = (const float*)d_in[1];
    const int*   a2b           = (const int*)d_in[2];
    const int*   mapping       = (const int*)d_in[3];
    const float* gfeat         = (const float*)d_in[4];
    const float* Wi            = (const float*)d_in[5];
    const float* Wh            = (const float*)d_in[6];
    const float* Wow           = (const float*)d_in[7];
    const float* Wob           = (const float*)d_in[8];

    char* ws = (char*)d_ws;
    size_t off = 0;
    auto alloc = [&](size_t bytes) {
        void* p = ws + off;
        off += (bytes + 255) & ~(size_t)255;
        return p;
    };
    bf16_t* WIH  = (bf16_t*)alloc((size_t)WROWS * LDW * 2);    // 0.31 MB
    bf16_t* WOM  = (bf16_t*)alloc((size_t)WROWS * LDW * 2);    // 0.31 MB
    bf16_t* msgA = (bf16_t*)alloc((size_t)NBND * D_HP * 2);    // 243.2 MB
    bf16_t* msgB = (bf16_t*)alloc((size_t)NBND * D_HP * 2);    // 243.2 MB
    bf16_t* atoms = msgB;   // msgB dead after MP round 2; atoms needs 121.6 MB

    if (off > ws_size) {
        float v = 1.0e6f + (float)(ws_size >> 20);
        fill_sentinel<<<1024, 256, 0, stream>>>((float*)d_out, out_size, v);
        return;
    }

    prep_weights<<<600, 256, 0, stream>>>(Wi, Wh, Wow, WIH, WOM);

    const int gb = (NBND + BM - 1) / BM;   // 6251
    const int ga = (NATM + BM - 1) / BM;   // 3125
    const size_t fmax = (size_t)NBND * IFD - 1;
    const size_t amax = (size_t)NATM * AFD - 1;

    // msgA = relu(f_ini @ Wi^T)
    gemm_mfma<false, false><<<gb, 256, 0, stream>>>(
        f_ini, nullptr, WIH, nullptr, nullptr, msgA,
        NBND, KT_S1, IFD, fmax);
    // msgB = relu(f_ini @ Wi^T + gather6(msgA) @ Wh^T)
    gemm_mfma<true, false><<<gb, 256, 0, stream>>>(
        f_ini, msgA, WIH, mapping, nullptr, msgB,
        NBND, KT_MP, IFD, fmax);
    // msgA = relu(f_ini @ Wi^T + gather6(msgB) @ Wh^T)
    gemm_mfma<true, false><<<gb, 256, 0, stream>>>(
        f_ini, msgB, WIH, mapping, nullptr, msgA,
        NBND, KT_MP, IFD, fmax);
    // atoms = relu(atom_features @ Woa^T + gather6(msgA) @ Wom^T + b)
    gemm_mfma<true, true><<<ga, 256, 0, stream>>>(
        atom_features, msgA, WOM, a2b, Wob, atoms,
        NATM, KT_MP, AFD, amax);

    readout<<<NMOLS, 320, 0, stream>>>(atoms, gfeat, (float*)d_out);
}